// Round 18
// baseline (642.233 us; speedup 1.0000x reference)
//
#include <hip/hip_runtime.h>
#include <math.h>

#define Bc 2
#define Hh 32
#define Ww 32
#define Cc 384
#define NHc 12
#define NGc 6
#define CGc 64
#define HCc 32
#define GHc 2
#define HIDc 1536
#define Lc 1024
#define NSc 1024
#define BGc 12

typedef float f32x4 __attribute__((ext_vector_type(4)));
typedef short bf16x8 __attribute__((ext_vector_type(8)));

__device__ __forceinline__ float gelu_f(float v) {
    return 0.5f * v * (1.f + erff(v * 0.70710678118654752440f));
}

__device__ __forceinline__ unsigned short f2bf(float f) {
    unsigned u = __float_as_uint(f);
    u = (u + 0x7FFF + ((u >> 16) & 1)) >> 16;   // RNE
    return (unsigned short)u;
}

__device__ __forceinline__ float bf2f(unsigned short u) {
    return __uint_as_float((unsigned)u << 16);
}

// ---------------- fused prep: weight casts + rpe table + LN1 -------------
__global__ __launch_bounds__(256) void prep_kernel(
    const float* __restrict__ wq, const float* __restrict__ wk,
    const float* __restrict__ wv, const float* __restrict__ wo,
    const float* __restrict__ f1, const float* __restrict__ f2,
    unsigned short* __restrict__ dq, unsigned short* __restrict__ dk,
    unsigned short* __restrict__ dv, unsigned short* __restrict__ d_o,
    unsigned short* __restrict__ d1, unsigned short* __restrict__ d2,
    const float* __restrict__ rpe, unsigned short* __restrict__ tbl,
    const float* __restrict__ x, const float* __restrict__ n1w,
    const float* __restrict__ n1b, unsigned short* __restrict__ xnbf)
{
    int bid = blockIdx.x;
    int tid = threadIdx.x;
    if (bid < 1728) {
        const float* s; unsigned short* d; int base;
        if (bid < 144)       { s = wq; d = dq;  base = bid; }
        else if (bid < 288)  { s = wk; d = dk;  base = bid - 144; }
        else if (bid < 432)  { s = wv; d = dv;  base = bid - 288; }
        else if (bid < 576)  { s = wo; d = d_o; base = bid - 432; }
        else if (bid < 1152) { s = f1; d = d1;  base = bid - 576; }
        else                 { s = f2; d = d2;  base = bid - 1152; }
        int i = base * 1024 + tid * 4;
        float4 v = *(const float4*)(s + i);
        ushort4 u;
        u.x = f2bf(v.x); u.y = f2bf(v.y); u.z = f2bf(v.z); u.w = f2bf(v.w);
        *(ushort4*)(d + i) = u;
    } else if (bid < 1920) {
        int blk = bid - 1728;
        int h = blk >> 4;
        int i = (blk & 15) * 256 + tid;
        unsigned short v = 0;
        if (i < 4095) {
            int row = i / 65, cx = i - row * 65;
            if (cx < 63) v = f2bf(rpe[h * 3969 + row * 63 + cx] * 1.44269504f);
        }
        tbl[(size_t)h * 4096 + i] = v;
    } else {
        __shared__ float l1[4], l2[4];
        int row = (bid - 1920) * 2 + (tid >> 7);
        int t = tid & 127;
        const float* xr = x + (size_t)row * Cc;
        float v0 = xr[t], v1 = xr[t + 128], v2 = xr[t + 256];
        float s = v0 + v1 + v2;
        #pragma unroll
        for (int o = 32; o; o >>= 1) s += __shfl_down(s, o);
        if ((tid & 63) == 0) l1[tid >> 6] = s;
        __syncthreads();
        int rbase = (tid >> 7) * 2;
        float mu = (l1[rbase] + l1[rbase + 1]) * (1.f / Cc);
        float d0 = v0 - mu, d1v = v1 - mu, d2v = v2 - mu;
        float q = d0 * d0 + d1v * d1v + d2v * d2v;
        #pragma unroll
        for (int o = 32; o; o >>= 1) q += __shfl_down(q, o);
        if ((tid & 63) == 0) l2[tid >> 6] = q;
        __syncthreads();
        float rstd = rsqrtf((l2[rbase] + l2[rbase + 1]) * (1.f / Cc) + 1e-5f);
        unsigned short* orow = xnbf + (size_t)row * Cc;
        orow[t]       = f2bf(d0 * rstd * n1w[t]       + n1b[t]);
        orow[t + 128] = f2bf(d1v * rstd * n1w[t + 128] + n1b[t + 128]);
        orow[t + 256] = f2bf(d2v * rstd * n1w[t + 256] + n1b[t + 256]);
    }
}

// ---------------- LayerNorm over C=384 -> bf16, one row per 128 thr -----
__global__ __launch_bounds__(128) void ln_kernel(
    const float* __restrict__ x, const float* __restrict__ w,
    const float* __restrict__ b, unsigned short* __restrict__ out)
{
    __shared__ float l1[2], l2[2];
    int row = blockIdx.x;
    int t = threadIdx.x;
    const float* xr = x + (size_t)row * Cc;
    float v0 = xr[t], v1 = xr[t + 128], v2 = xr[t + 256];
    float s = v0 + v1 + v2;
    #pragma unroll
    for (int o = 32; o; o >>= 1) s += __shfl_down(s, o);
    if ((t & 63) == 0) l1[t >> 6] = s;
    __syncthreads();
    float mu = (l1[0] + l1[1]) * (1.f / Cc);
    float d0 = v0 - mu, d1 = v1 - mu, d2 = v2 - mu;
    float q = d0 * d0 + d1 * d1 + d2 * d2;
    #pragma unroll
    for (int o = 32; o; o >>= 1) q += __shfl_down(q, o);
    if ((t & 63) == 0) l2[t >> 6] = q;
    __syncthreads();
    float rstd = rsqrtf((l2[0] + l2[1]) * (1.f / Cc) + 1e-5f);
    unsigned short* orow = out + (size_t)row * Cc;
    orow[t]       = f2bf(d0 * rstd * w[t]       + b[t]);
    orow[t + 128] = f2bf(d1 * rstd * w[t + 128] + b[t + 128]);
    orow[t + 256] = f2bf(d2 * rstd * w[t + 256] + b[t + 256]);
}

// ---------------- bf16 MFMA GEMM: wave tile 16m x 32n (R16 validated) ----
// EPI 1: gelu -> bf16; EPI 2: +res -> f32; EPI 3: dual q-store.
template<int EPI>
__global__ __launch_bounds__(256) void mfma_gemm(
    const unsigned short* __restrict__ A, const unsigned short* __restrict__ W,
    const float* __restrict__ bias, const float* __restrict__ res,
    void* __restrict__ out1, void* __restrict__ out2, int M, int N, int K)
{
    int w = threadIdx.x >> 6, l = threadIdx.x & 63;
    int col = l & 15, quad = l >> 4;
    int mb = blockIdx.x * 64 + w * 16;
    int n0 = blockIdx.y * 32;
    const unsigned short* Ap = A + (size_t)(mb + col) * K + quad * 8;
    const unsigned short* Wp0 = W + (size_t)(n0 + col) * K + quad * 8;
    const unsigned short* Wp1 = W + (size_t)(n0 + 16 + col) * K + quad * 8;
    f32x4 acc[2] = {};
    #pragma unroll 4
    for (int k0 = 0; k0 < K; k0 += 32) {
        bf16x8 af = *(const bf16x8*)(Ap + k0);
        bf16x8 w0 = *(const bf16x8*)(Wp0 + k0);
        bf16x8 w1 = *(const bf16x8*)(Wp1 + k0);
        acc[0] = __builtin_amdgcn_mfma_f32_16x16x32_bf16(af, w0, acc[0], 0, 0, 0);
        acc[1] = __builtin_amdgcn_mfma_f32_16x16x32_bf16(af, w1, acc[1], 0, 0, 0);
    }
    int bb = mb >> 10, l0 = (mb & 1023) + quad * 4;
    #pragma unroll
    for (int ch = 0; ch < 2; ch++) {
        int n = n0 + ch * 16 + col;
        float bv = bias[n];
        if (EPI == 3) {
            unsigned short u0 = f2bf(acc[ch][0] + bv);
            unsigned short u1 = f2bf(acc[ch][1] + bv);
            unsigned short u2 = f2bf(acc[ch][2] + bv);
            unsigned short u3 = f2bf(acc[ch][3] + bv);
            ushort4 qv = {u0, u1, u2, u3};
            *(ushort4*)&((unsigned short*)out1)[((size_t)(bb * Cc + n)) * Lc + l0] = qv;
            unsigned short* q2 = (unsigned short*)out2;
            size_t base = (((size_t)(bb * NHc + (n >> 5))) * Lc + l0) * 32 + (n & 31);
            q2[base] = u0; q2[base + 32] = u1; q2[base + 64] = u2; q2[base + 96] = u3;
        } else {
            #pragma unroll
            for (int r = 0; r < 4; r++) {
                size_t m = mb + quad * 4 + r;
                float v = acc[ch][r] + bv;
                if (EPI == 1)
                    ((unsigned short*)out1)[m * N + n] = f2bf(gelu_f(v));
                else
                    ((float*)out1)[m * N + n] = v + res[m * N + n];
            }
        }
    }
}

// ---------------- fused k+v projection (shared A fragments), 32n --------
__global__ __launch_bounds__(256) void mfma_kv(
    const unsigned short* __restrict__ A, const unsigned short* __restrict__ Wk,
    const unsigned short* __restrict__ Wv, const float* __restrict__ bk,
    const float* __restrict__ bv, unsigned short* __restrict__ kout,
    unsigned short* __restrict__ vout, int M, int K)
{
    int w = threadIdx.x >> 6, l = threadIdx.x & 63;
    int col = l & 15, quad = l >> 4;
    int mb = blockIdx.x * 64 + w * 16;
    int n0 = blockIdx.y * 32;
    const unsigned short* Ap = A + (size_t)(mb + col) * K + quad * 8;
    const unsigned short* Wk0 = Wk + (size_t)(n0 + col) * K + quad * 8;
    const unsigned short* Wk1 = Wk + (size_t)(n0 + 16 + col) * K + quad * 8;
    const unsigned short* Wv0 = Wv + (size_t)(n0 + col) * K + quad * 8;
    const unsigned short* Wv1 = Wv + (size_t)(n0 + 16 + col) * K + quad * 8;
    f32x4 ak[2] = {}, av[2] = {};
    #pragma unroll 4
    for (int k0 = 0; k0 < K; k0 += 32) {
        bf16x8 af = *(const bf16x8*)(Ap + k0);
        bf16x8 k0f = *(const bf16x8*)(Wk0 + k0);
        bf16x8 k1f = *(const bf16x8*)(Wk1 + k0);
        bf16x8 v0f = *(const bf16x8*)(Wv0 + k0);
        bf16x8 v1f = *(const bf16x8*)(Wv1 + k0);
        ak[0] = __builtin_amdgcn_mfma_f32_16x16x32_bf16(af, k0f, ak[0], 0, 0, 0);
        ak[1] = __builtin_amdgcn_mfma_f32_16x16x32_bf16(af, k1f, ak[1], 0, 0, 0);
        av[0] = __builtin_amdgcn_mfma_f32_16x16x32_bf16(af, v0f, av[0], 0, 0, 0);
        av[1] = __builtin_amdgcn_mfma_f32_16x16x32_bf16(af, v1f, av[1], 0, 0, 0);
    }
    int bb = mb >> 10, l0 = (mb & 1023) + quad * 4;
    #pragma unroll
    for (int ch = 0; ch < 2; ch++) {
        int n = n0 + ch * 16 + col;
        float bkv = bk[n], bvv = bv[n];
        #pragma unroll
        for (int r = 0; r < 4; r++)
            kout[(size_t)(mb + quad * 4 + r) * Cc + n] = f2bf(ak[ch][r] + bkv);
        ushort4 u;
        u.x = f2bf(av[ch][0] + bvv); u.y = f2bf(av[ch][1] + bvv);
        u.z = f2bf(av[ch][2] + bvv); u.w = f2bf(av[ch][3] + bvv);
        *(ushort4*)&vout[((size_t)(bb * Cc + n)) * NSc + l0] = u;
    }
}

// ---------------- Depthwise 7x7 conv (bf16 in, f32 out), LDS-staged ------
__global__ __launch_bounds__(256) void dwconv_kernel(
    const unsigned short* __restrict__ q, const float* __restrict__ wdw,
    const float* __restrict__ bdw, float* __restrict__ o_dw)
{
    int cg = blockIdx.x, bg = blockIdx.y;
    int b = bg / NGc, g = bg % NGc;
    __shared__ float wk_s[49];
    __shared__ float img[1024];
    const unsigned short* qp = q + (size_t)(b * Cc + g * CGc + cg) * Lc;
    if (threadIdx.x < 49) wk_s[threadIdx.x] = wdw[cg * 49 + threadIdx.x];
    #pragma unroll
    for (int i = 0; i < 4; i++)
        img[threadIdx.x + i * 256] = bf2f(qp[threadIdx.x + i * 256]);
    __syncthreads();
    float bias = bdw[cg];
    #pragma unroll
    for (int i = 0; i < 4; i++) {
        int hw = threadIdx.x + i * 256;
        int y = hw >> 5, xx = hw & 31;
        float acc = bias;
        #pragma unroll
        for (int ky = 0; ky < 7; ky++) {
            int yy = y + ky - 3;
            if (yy < 0 || yy > 31) continue;
            #pragma unroll
            for (int kx = 0; kx < 7; kx++) {
                int x2 = xx + kx - 3;
                if (x2 < 0 || x2 > 31) continue;
                acc += img[yy * 32 + x2] * wk_s[ky * 7 + kx];
            }
        }
        o_dw[(size_t)(bg * CGc + cg) * Lc + hw] = acc;
    }
}

// ---------------- fused offset head + grid-sample ------------------------
__global__ __launch_bounds__(256) void offsample_kernel(
    const float* __restrict__ o_dw, const float* __restrict__ lnw,
    const float* __restrict__ lnb, const float* __restrict__ pw,
    const unsigned short* __restrict__ xn, float* __restrict__ pos,
    unsigned short* __restrict__ xs)
{
    int hw = blockIdx.x * 4 + (threadIdx.x >> 6);
    int bg = blockIdx.y;
    int cg = threadIdx.x & 63;
    int b = bg / NGc, g = bg % NGc;
    float v = o_dw[(size_t)(bg * CGc + cg) * Lc + hw];
    float s = v;
    #pragma unroll
    for (int o = 32; o; o >>= 1) s += __shfl_down(s, o);
    s = __shfl(s, 0, 64);
    float mu = s * (1.f / CGc);
    float d = v - mu;
    float q2 = d * d;
    #pragma unroll
    for (int o = 32; o; o >>= 1) q2 += __shfl_down(q2, o);
    q2 = __shfl(q2, 0, 64);
    float rstd = rsqrtf(q2 * (1.f / CGc) + 1e-5f);
    float t = d * rstd * lnw[cg] + lnb[cg];
    float gl = gelu_f(t);
    float sy = gl * pw[cg];
    float sx = gl * pw[CGc + cg];
    #pragma unroll
    for (int o = 32; o; o >>= 1) {
        sy += __shfl_down(sy, o);
        sx += __shfl_down(sx, o);
    }
    sy = __shfl(sy, 0, 64);
    sx = __shfl(sx, 0, 64);
    int y = hw >> 5, xx = hw & 31;
    float py = tanhf(sy) * 0.0625f + ((y + 0.5f) * (2.f / Hh) - 1.f);
    float px = tanhf(sx) * 0.0625f + ((xx + 0.5f) * (2.f / Ww) - 1.f);
    if (cg == 0) {
        pos[((size_t)bg * Lc + hw) * 2 + 0] = py;
        pos[((size_t)bg * Lc + hw) * 2 + 1] = px;
    }
    float fx = (px + 1.f) * 0.5f * 31.f;
    float fy = (py + 1.f) * 0.5f * 31.f;
    float x0f = floorf(fx), y0f = floorf(fy);
    int x0 = (int)x0f, y0 = (int)y0f;
    float wx1 = fx - x0f, wy1 = fy - y0f;
    float wx0 = 1.f - wx1, wy0 = 1.f - wy1;
    const unsigned short* base = xn + (size_t)(b * Lc) * Cc + g * CGc + cg;
    float acc = 0.f;
    if (y0 >= 0 && y0 <= 31) {
        if (x0 >= 0 && x0 <= 31) acc += bf2f(base[(size_t)(y0 * 32 + x0) * Cc]) * wx0 * wy0;
        if (x0 + 1 >= 0 && x0 + 1 <= 31) acc += bf2f(base[(size_t)(y0 * 32 + x0 + 1) * Cc]) * wx1 * wy0;
    }
    if (y0 + 1 >= 0 && y0 + 1 <= 31) {
        if (x0 >= 0 && x0 <= 31) acc += bf2f(base[(size_t)((y0 + 1) * 32 + x0) * Cc]) * wx0 * wy1;
        if (x0 + 1 >= 0 && x0 + 1 <= 31) acc += bf2f(base[(size_t)((y0 + 1) * 32 + x0 + 1) * Cc]) * wx1 * wy1;
    }
    xs[((size_t)(b * NSc) + hw) * Cc + g * CGc + cg] = f2bf(acc);
}

// ---------------- MFMA flash attention v11: split-n x2, self-merging -----
// R16 structure + last-block-reduces: each half writes f32 partials, bumps
// a per-(b,h,mtile) counter (memset to 0 each call); the second finisher
// reads both halves, sums, divides, writes attnbf. Kills the merge kernel
// + one launch gap. No dispatch-order assumption (G16-safe: device-scope
// atomics + threadfence; no spinning).
__global__ __launch_bounds__(256) void attn_kernel(
    const unsigned short* __restrict__ qbf, const unsigned short* __restrict__ kbf,
    const unsigned short* __restrict__ vtb, const float* __restrict__ pos,
    const unsigned short* __restrict__ rpet, float* __restrict__ pO,
    float* __restrict__ pL, int* __restrict__ cnt,
    unsigned short* __restrict__ attno)
{
    __shared__ float o_smem[2112];               // o_s overlay [4][16][33]
    __shared__ unsigned short p_bf[4][16 * 72];  // per-wave P tile
    __shared__ float l_s[4][16];
    __shared__ int arrive;
    unsigned short* rpe_s = (unsigned short*)o_smem;  // [63][65] bf16*log2e

    int m0 = blockIdx.x * 16;
    int h = blockIdx.y >> 1, half = blockIdx.y & 1;
    int b = blockIdx.z;
    int tid = threadIdx.x;
    int w = tid >> 6, l = tid & 63;
    int col = l & 15, quad = l >> 4;

    {   // raw vector copy of the precomputed LDS image (4096 entries)
        const unsigned short* tbh = rpet + (size_t)h * 4096;
        #pragma unroll
        for (int i = 0; i < 4; i++) {
            int idx = (tid + i * 256) * 4;
            *(ushort4*)(rpe_s + idx) = *(const ushort4*)(tbh + idx);
        }
    }

    bf16x8 qfrag = *(const bf16x8*)(qbf +
        ((((size_t)(b * NHc + h)) * Lc + m0 + col) * 32 + quad * 8));

    float qgy = ((m0 >> 5) + 0.5f) * (2.f / 32.f) - 1.f;
    float qgx0 = (((m0 & 31) + quad * 4) + 0.5f) * (2.f / 32.f) - 1.f;

    const unsigned short* kb_ = kbf + (size_t)b * NSc * Cc + h * HCc;
    const unsigned short* vb_ = vtb + ((size_t)(b * Cc + h * HCc)) * NSc;
    const float2* pp = (const float2*)(pos + (size_t)(b * NGc + (h >> 1)) * NSc * 2);

    float run_l[4] = {0.f, 0.f, 0.f, 0.f};
    f32x4 O0 = {0.f, 0.f, 0.f, 0.f};
    f32x4 O1 = {0.f, 0.f, 0.f, 0.f};

    __syncthreads();   // rpe_s staged

    for (int it = 0; it < 2; it++) {
        int n0 = half * 512 + w * 128 + it * 64;
        // ---- QK^T ----
        f32x4 s[4];
        #pragma unroll
        for (int ch = 0; ch < 4; ch++) {
            bf16x8 kf = *(const bf16x8*)(kb_ +
                ((size_t)(n0 + ch * 16 + col) * Cc + quad * 8));
            f32x4 z = {0.f, 0.f, 0.f, 0.f};
            s[ch] = __builtin_amdgcn_mfma_f32_16x16x32_bf16(qfrag, kf, z, 0, 0, 0);
        }
        // ---- scale(log2e) + RPE bias from bf16 LDS table ----
        #pragma unroll
        for (int ch = 0; ch < 4; ch++) {
            int n = n0 + ch * 16 + col;
            float2 pyx = pp[n];
            float fy = ((qgy - pyx.x) * 0.5f + 1.f) * 31.f;
            float y0f = floorf(fy);
            int iy = (int)y0f;
            float wy1 = fy - y0f, wy0 = 1.f - wy1;
            bool y0ok = (unsigned)iy <= 62u;
            bool y1ok = (unsigned)(iy + 1) <= 62u;
            const unsigned short* r0 = rpe_s + iy * 65;
            float fx0 = ((qgx0 - pyx.y) * 0.5f + 1.f) * 31.f;
            #pragma unroll
            for (int r = 0; r < 4; r++) {
                float fx = fx0 + r * 0.96875f;
                float x0f = floorf(fx);
                int ix = (int)x0f;
                float wx1 = fx - x0f, wx0 = 1.f - wx1;
                bool x0ok = (unsigned)ix <= 62u;
                bool x1ok = (unsigned)(ix + 1) <= 62u;
                float bias = 0.f;
                if (y0ok) {
                    if (x0ok) bias += bf2f(r0[ix]) * wy0 * wx0;
                    if (x1ok) bias += bf2f(r0[ix + 1]) * wy0 * wx1;
                }
                if (y1ok) {
                    if (x0ok) bias += bf2f(r0[65 + ix]) * wy1 * wx0;
                    if (x1ok) bias += bf2f(r0[65 + ix + 1]) * wy1 * wx1;
                }
                // 0.17677669529663688 * log2(e)
                s[ch][r] = s[ch][r] * 0.25506974f + bias;
            }
        }
        // ---- max-free softmax accumulation (exp2 domain) ----
        float rowsum[4] = {0.f, 0.f, 0.f, 0.f};
        #pragma unroll
        for (int ch = 0; ch < 4; ch++)
            #pragma unroll
            for (int r = 0; r < 4; r++) {
                float e = exp2f(s[ch][r]);
                s[ch][r] = e;
                rowsum[r] += e;
            }
        #pragma unroll
        for (int r = 0; r < 4; r++) run_l[r] += rowsum[r];
        // ---- P -> wave-private LDS (C-layout -> A-layout) ----
        #pragma unroll
        for (int ch = 0; ch < 4; ch++)
            #pragma unroll
            for (int r = 0; r < 4; r++)
                p_bf[w][(quad * 4 + r) * 72 + ch * 16 + col] = f2bf(s[ch][r]);
        // ---- PV ----
        #pragma unroll
        for (int hn = 0; hn < 2; hn++) {
            bf16x8 pf = *(const bf16x8*)&p_bf[w][col * 72 + hn * 32 + quad * 8];
            bf16x8 v0 = *(const bf16x8*)(vb_ +
                ((size_t)col * NSc + n0 + hn * 32 + quad * 8));
            O0 = __builtin_amdgcn_mfma_f32_16x16x32_bf16(pf, v0, O0, 0, 0, 0);
            bf16x8 v1 = *(const bf16x8*)(vb_ +
                ((size_t)(col + 16) * NSc + n0 + hn * 32 + quad * 8));
            O1 = __builtin_amdgcn_mfma_f32_16x16x32_bf16(pf, v1, O1, 0, 0, 0);
        }
    }
    // ---- reduce row-sums across the quad's 16 lanes ----
    #pragma unroll
    for (int r = 0; r < 4; r++) {
        float sm = run_l[r];
        #pragma unroll
        for (int msk = 1; msk < 16; msk <<= 1)
            sm += __shfl_xor(sm, msk);
        run_l[r] = sm;
    }
    __syncthreads();   // all rpe_s reads done before o_s overlay
    float* o_s = o_smem;
    #pragma unroll
    for (int r = 0; r < 4; r++) {
        int m = quad * 4 + r;
        o_s[w * 528 + m * 33 + col] = O0[r];
        o_s[w * 528 + m * 33 + col + 16] = O1[r];
    }
    if (col == 0) {
        #pragma unroll
        for (int r = 0; r < 4; r++)
            l_s[w][quad * 4 + r] = run_l[r];
    }
    __syncthreads();
    // ---- write own f32 partials (plain sums) ----
    int bhmt = ((b * NHc + h) << 6) + blockIdx.x;   // (b,h,mtile) id
    size_t tile = (size_t)bhmt * 2 + half;
    for (int i = tid; i < 512; i += 256) {
        int m = i >> 5, c = i & 31;
        float osum = o_s[0 * 528 + m * 33 + c] + o_s[1 * 528 + m * 33 + c]
                   + o_s[2 * 528 + m * 33 + c] + o_s[3 * 528 + m * 33 + c];
        pO[tile * 512 + i] = osum;
        if (c == 0)
            pL[tile * 16 + m] = l_s[0][m] + l_s[1][m] + l_s[2][m] + l_s[3][m];
    }
    __threadfence();   // partials visible before arrival announcement
    if (tid == 0) arrive = atomicAdd(&cnt[bhmt], 1);
    __syncthreads();
    if (arrive != 1) return;   // first finisher exits; second merges
    __threadfence();           // acquire other half's partials
    size_t other = (size_t)bhmt * 2 + (half ^ 1);
    for (int i = tid; i < 512; i += 256) {
        int m = i >> 5, c = i & 31;
        float lsum = pL[tile * 16 + m] + pL[other * 16 + m];
        float o = pO[tile * 512 + i] + pO[other * 512 + i];
        attno[((size_t)(b * Lc) + m0 + m) * Cc + h * HCc + c] = f2bf(o / lsum);
    }
}

extern "C" void kernel_launch(void* const* d_in, const int* in_sizes, int n_in,
                              void* d_out, int out_size, void* d_ws, size_t ws_size,
                              hipStream_t stream)
{
    const float* x    = (const float*)d_in[0];
    const float* n1w  = (const float*)d_in[1];
    const float* n1b  = (const float*)d_in[2];
    const float* wq   = (const float*)d_in[3];
    const float* bq   = (const float*)d_in[4];
    const float* wk   = (const float*)d_in[5];
    const float* bk   = (const float*)d_in[6];
    const float* wv   = (const float*)d_in[7];
    const float* bv   = (const float*)d_in[8];
    const float* wo   = (const float*)d_in[9];
    const float* bo   = (const float*)d_in[10];
    const float* dw_w = (const float*)d_in[11];
    const float* dw_b = (const float*)d_in[12];
    const float* lnw  = (const float*)d_in[13];
    const float* lnb  = (const float*)d_in[14];
    const float* pw_w = (const float*)d_in[15];
    const float* rpe  = (const float*)d_in[16];
    const float* n2w  = (const float*)d_in[17];
    const float* n2b  = (const float*)d_in[18];
    const float* fc1w = (const float*)d_in[19];
    const float* fc1b = (const float*)d_in[20];
    const float* fc2w = (const float*)d_in[21];
    const float* fc2b = (const float*)d_in[22];
    float* out = (float*)d_out;

    float* ws = (float*)d_ws;
    unsigned short* xnbf = (unsigned short*)ws;                  // (B,L,C) bf16
    unsigned short* qb16 = (unsigned short*)(ws + 393216);       // (B,C,L) bf16
    unsigned short* qbf  = (unsigned short*)(ws + 1179648);      // (B,NH,L,32) bf16
    unsigned short* h1bf = (unsigned short*)ws;                  // (B*L,HID) bf16 (overlay)
    float* pO    = ws;                                           // 3072*512 f32 (overlay)
    float* pL    = ws + 1572864;                                 // 3072*16 f32
    float* odw   = ws + 1671168;                                 // (BG,CG,L) f32
    unsigned short* xln2bf = (unsigned short*)(ws + 1671168);    // overlay odw
    float* posb  = ws + 2457600;                                 // (BG,NS,2) f32
    unsigned short* xsbf = (unsigned short*)(ws + 2482176);      // (B,NS,C) bf16
    unsigned short* kbf  = (unsigned short*)(ws + 2875392);      // (B,NS,C) bf16
    unsigned short* vtb  = (unsigned short*)(ws + 3268608);      // (B,C,NS) bf16
    unsigned short* attnbf = (unsigned short*)(ws + 3661824);    // (B,L,C) bf16
    float* x2    = ws + 4055040;                                 // (B,L,C) f32
    unsigned short* wqbf   = (unsigned short*)(ws + 4841472);
    unsigned short* wkbf   = (unsigned short*)(ws + 4915200);
    unsigned short* wvbf   = (unsigned short*)(ws + 4988928);
    unsigned short* wobf   = (unsigned short*)(ws + 5062656);
    unsigned short* fc1wbf = (unsigned short*)(ws + 5136384);
    unsigned short* fc2wbf = (unsigned short*)(ws + 5431296);
    unsigned short* rpet   = (unsigned short*)(ws + 5726208);    // 12*4096 us
    int* cnt = (int*)(ws + 5750784);                             // 1536 ints

    // counters must start at 0 every call (ws is re-poisoned to 0xAA)
    hipMemsetAsync(cnt, 0, 1536 * sizeof(int), stream);
    // 0. fused prep: weight casts + rpe table + LN1 (one launch)
    prep_kernel<<<2944, 256, 0, stream>>>(
        wq, wk, wv, wo, fc1w, fc2w, wqbf, wkbf, wvbf, wobf, fc1wbf, fc2wbf,
        rpe, rpet, x, n1w, n1b, xnbf);
    // 1. q projection (MFMA): dual-store bf16 (B,C,L) + bf16 (B,NH,L,32)
    mfma_gemm<3><<<dim3(Bc * Lc / 64, Cc / 32), 256, 0, stream>>>(
        xnbf, wqbf, bq, x, qb16, qbf, Bc * Lc, Cc, Cc);
    // 2. depthwise 7x7 (bf16 in)
    dwconv_kernel<<<dim3(CGc, BGc), 256, 0, stream>>>(qb16, dw_w, dw_b, odw);
    // 3. fused offset head + grid-sample -> pos + xsbf
    offsample_kernel<<<dim3(Lc / 4, BGc), 256, 0, stream>>>(
        odw, lnw, lnb, pw_w, xnbf, posb, xsbf);
    // 4. fused k+v projection
    mfma_kv<<<dim3(Bc * NSc / 64, Cc / 32), 256, 0, stream>>>(
        xsbf, wkbf, wvbf, bk, bv, kbf, vtb, Bc * NSc, Cc);
    // 5. MFMA flash attention, n-split x2, self-merging -> bf16 (B,L,C)
    attn_kernel<<<dim3(Lc / 16, NHc * 2, Bc), 256, 0, stream>>>(
        qbf, kbf, vtb, posb, rpet, pO, pL, cnt, attnbf);
    // 6. out projection + residual (MFMA) -> x2 f32 (B,L,C)
    mfma_gemm<2><<<dim3(Bc * Lc / 64, Cc / 32), 256, 0, stream>>>(
        attnbf, wobf, bo, x, x2, x2, Bc * Lc, Cc, Cc);
    // 7. LN2 -> bf16
    ln_kernel<<<Bc * Lc, 128, 0, stream>>>(x2, n2w, n2b, xln2bf);
    // 8. fc1 + GELU (MFMA) -> h1 bf16
    mfma_gemm<1><<<dim3(Bc * Lc / 64, HIDc / 32), 256, 0, stream>>>(
        xln2bf, fc1wbf, fc1b, x2, h1bf, h1bf, Bc * Lc, HIDc, Cc);
    // 9. fc2 + residual (MFMA) -> out f32
    mfma_gemm<2><<<dim3(Bc * Lc / 64, Cc / 32), 256, 0, stream>>>(
        h1bf, fc2wbf, fc2b, x2, out, out, Bc * Lc, Cc, HIDc);
}

// Round 19
// 271.681 us; speedup vs baseline: 2.3639x; 2.3639x over previous
//
#include <hip/hip_runtime.h>
#include <math.h>

#define Bc 2
#define Hh 32
#define Ww 32
#define Cc 384
#define NHc 12
#define NGc 6
#define CGc 64
#define HCc 32
#define GHc 2
#define HIDc 1536
#define Lc 1024
#define NSc 1024
#define BGc 12

typedef float f32x4 __attribute__((ext_vector_type(4)));
typedef short bf16x8 __attribute__((ext_vector_type(8)));

__device__ __forceinline__ float gelu_f(float v) {
    return 0.5f * v * (1.f + erff(v * 0.70710678118654752440f));
}

__device__ __forceinline__ unsigned short f2bf(float f) {
    unsigned u = __float_as_uint(f);
    u = (u + 0x7FFF + ((u >> 16) & 1)) >> 16;   // RNE
    return (unsigned short)u;
}

__device__ __forceinline__ float bf2f(unsigned short u) {
    return __uint_as_float((unsigned)u << 16);
}

// ---------------- fused prep: weight casts + rpe table + LN1 -------------
__global__ __launch_bounds__(256) void prep_kernel(
    const float* __restrict__ wq, const float* __restrict__ wk,
    const float* __restrict__ wv, const float* __restrict__ wo,
    const float* __restrict__ f1, const float* __restrict__ f2,
    unsigned short* __restrict__ dq, unsigned short* __restrict__ dk,
    unsigned short* __restrict__ dv, unsigned short* __restrict__ d_o,
    unsigned short* __restrict__ d1, unsigned short* __restrict__ d2,
    const float* __restrict__ rpe, unsigned short* __restrict__ tbl,
    const float* __restrict__ x, const float* __restrict__ n1w,
    const float* __restrict__ n1b, unsigned short* __restrict__ xnbf)
{
    int bid = blockIdx.x;
    int tid = threadIdx.x;
    if (bid < 1728) {
        const float* s; unsigned short* d; int base;
        if (bid < 144)       { s = wq; d = dq;  base = bid; }
        else if (bid < 288)  { s = wk; d = dk;  base = bid - 144; }
        else if (bid < 432)  { s = wv; d = dv;  base = bid - 288; }
        else if (bid < 576)  { s = wo; d = d_o; base = bid - 432; }
        else if (bid < 1152) { s = f1; d = d1;  base = bid - 576; }
        else                 { s = f2; d = d2;  base = bid - 1152; }
        int i = base * 1024 + tid * 4;
        float4 v = *(const float4*)(s + i);
        ushort4 u;
        u.x = f2bf(v.x); u.y = f2bf(v.y); u.z = f2bf(v.z); u.w = f2bf(v.w);
        *(ushort4*)(d + i) = u;
    } else if (bid < 1920) {
        int blk = bid - 1728;
        int h = blk >> 4;
        int i = (blk & 15) * 256 + tid;
        unsigned short v = 0;
        if (i < 4095) {
            int row = i / 65, cx = i - row * 65;
            if (cx < 63) v = f2bf(rpe[h * 3969 + row * 63 + cx] * 1.44269504f);
        }
        tbl[(size_t)h * 4096 + i] = v;
    } else {
        __shared__ float l1[4], l2[4];
        int row = (bid - 1920) * 2 + (tid >> 7);
        int t = tid & 127;
        const float* xr = x + (size_t)row * Cc;
        float v0 = xr[t], v1 = xr[t + 128], v2 = xr[t + 256];
        float s = v0 + v1 + v2;
        #pragma unroll
        for (int o = 32; o; o >>= 1) s += __shfl_down(s, o);
        if ((tid & 63) == 0) l1[tid >> 6] = s;
        __syncthreads();
        int rbase = (tid >> 7) * 2;
        float mu = (l1[rbase] + l1[rbase + 1]) * (1.f / Cc);
        float d0 = v0 - mu, d1v = v1 - mu, d2v = v2 - mu;
        float q = d0 * d0 + d1v * d1v + d2v * d2v;
        #pragma unroll
        for (int o = 32; o; o >>= 1) q += __shfl_down(q, o);
        if ((tid & 63) == 0) l2[tid >> 6] = q;
        __syncthreads();
        float rstd = rsqrtf((l2[rbase] + l2[rbase + 1]) * (1.f / Cc) + 1e-5f);
        unsigned short* orow = xnbf + (size_t)row * Cc;
        orow[t]       = f2bf(d0 * rstd * n1w[t]       + n1b[t]);
        orow[t + 128] = f2bf(d1v * rstd * n1w[t + 128] + n1b[t + 128]);
        orow[t + 256] = f2bf(d2v * rstd * n1w[t + 256] + n1b[t + 256]);
    }
}

// ---------------- LayerNorm over C=384 -> bf16, one row per 128 thr -----
__global__ __launch_bounds__(128) void ln_kernel(
    const float* __restrict__ x, const float* __restrict__ w,
    const float* __restrict__ b, unsigned short* __restrict__ out)
{
    __shared__ float l1[2], l2[2];
    int row = blockIdx.x;
    int t = threadIdx.x;
    const float* xr = x + (size_t)row * Cc;
    float v0 = xr[t], v1 = xr[t + 128], v2 = xr[t + 256];
    float s = v0 + v1 + v2;
    #pragma unroll
    for (int o = 32; o; o >>= 1) s += __shfl_down(s, o);
    if ((t & 63) == 0) l1[t >> 6] = s;
    __syncthreads();
    float mu = (l1[0] + l1[1]) * (1.f / Cc);
    float d0 = v0 - mu, d1 = v1 - mu, d2 = v2 - mu;
    float q = d0 * d0 + d1 * d1 + d2 * d2;
    #pragma unroll
    for (int o = 32; o; o >>= 1) q += __shfl_down(q, o);
    if ((t & 63) == 0) l2[t >> 6] = q;
    __syncthreads();
    float rstd = rsqrtf((l2[0] + l2[1]) * (1.f / Cc) + 1e-5f);
    unsigned short* orow = out + (size_t)row * Cc;
    orow[t]       = f2bf(d0 * rstd * w[t]       + b[t]);
    orow[t + 128] = f2bf(d1 * rstd * w[t + 128] + b[t + 128]);
    orow[t + 256] = f2bf(d2 * rstd * w[t + 256] + b[t + 256]);
}

// ---------------- bf16 MFMA GEMM: wave tile 16m x 32n (R16 validated) ----
// EPI 1: gelu -> bf16; EPI 2: +res -> f32; EPI 3: dual q-store.
template<int EPI>
__global__ __launch_bounds__(256) void mfma_gemm(
    const unsigned short* __restrict__ A, const unsigned short* __restrict__ W,
    const float* __restrict__ bias, const float* __restrict__ res,
    void* __restrict__ out1, void* __restrict__ out2, int M, int N, int K)
{
    int w = threadIdx.x >> 6, l = threadIdx.x & 63;
    int col = l & 15, quad = l >> 4;
    int mb = blockIdx.x * 64 + w * 16;
    int n0 = blockIdx.y * 32;
    const unsigned short* Ap = A + (size_t)(mb + col) * K + quad * 8;
    const unsigned short* Wp0 = W + (size_t)(n0 + col) * K + quad * 8;
    const unsigned short* Wp1 = W + (size_t)(n0 + 16 + col) * K + quad * 8;
    f32x4 acc[2] = {};
    #pragma unroll 4
    for (int k0 = 0; k0 < K; k0 += 32) {
        bf16x8 af = *(const bf16x8*)(Ap + k0);
        bf16x8 w0 = *(const bf16x8*)(Wp0 + k0);
        bf16x8 w1 = *(const bf16x8*)(Wp1 + k0);
        acc[0] = __builtin_amdgcn_mfma_f32_16x16x32_bf16(af, w0, acc[0], 0, 0, 0);
        acc[1] = __builtin_amdgcn_mfma_f32_16x16x32_bf16(af, w1, acc[1], 0, 0, 0);
    }
    int bb = mb >> 10, l0 = (mb & 1023) + quad * 4;
    #pragma unroll
    for (int ch = 0; ch < 2; ch++) {
        int n = n0 + ch * 16 + col;
        float bv = bias[n];
        if (EPI == 3) {
            unsigned short u0 = f2bf(acc[ch][0] + bv);
            unsigned short u1 = f2bf(acc[ch][1] + bv);
            unsigned short u2 = f2bf(acc[ch][2] + bv);
            unsigned short u3 = f2bf(acc[ch][3] + bv);
            ushort4 qv = {u0, u1, u2, u3};
            *(ushort4*)&((unsigned short*)out1)[((size_t)(bb * Cc + n)) * Lc + l0] = qv;
            unsigned short* q2 = (unsigned short*)out2;
            size_t base = (((size_t)(bb * NHc + (n >> 5))) * Lc + l0) * 32 + (n & 31);
            q2[base] = u0; q2[base + 32] = u1; q2[base + 64] = u2; q2[base + 96] = u3;
        } else {
            #pragma unroll
            for (int r = 0; r < 4; r++) {
                size_t m = mb + quad * 4 + r;
                float v = acc[ch][r] + bv;
                if (EPI == 1)
                    ((unsigned short*)out1)[m * N + n] = f2bf(gelu_f(v));
                else
                    ((float*)out1)[m * N + n] = v + res[m * N + n];
            }
        }
    }
}

// ---------------- o-projection with fused attn merge ---------------------
// A-fragment built in-register from the two bf16 n-half partials + pL:
// A[m][h*32+c] = (pO0 + pO1) / (l0 + l1). Kills the merge kernel without
// any cross-block synchronization (R18's threadfence scheme was a 6x
// regression — device-scope fences drain L2 to HBM per block on gfx950).
__global__ __launch_bounds__(256) void mfma_oproj(
    const unsigned short* __restrict__ pO, const float* __restrict__ pL,
    const unsigned short* __restrict__ W, const float* __restrict__ bias,
    const float* __restrict__ res, float* __restrict__ out1, int M, int N, int K)
{
    int w = threadIdx.x >> 6, l = threadIdx.x & 63;
    int col = l & 15, quad = l >> 4;
    int mb = blockIdx.x * 64 + w * 16;
    int n0 = blockIdx.y * 32;
    int m = mb + col;
    int bb = m >> 10, ml = m & 1023;
    int mtile = ml >> 4, mm = ml & 15;
    const unsigned short* Wp0 = W + (size_t)(n0 + col) * K + quad * 8;
    const unsigned short* Wp1 = W + (size_t)(n0 + 16 + col) * K + quad * 8;
    f32x4 acc[2] = {};
    #pragma unroll 4
    for (int k0 = 0; k0 < K; k0 += 32) {
        int h = k0 >> 5;
        size_t t0 = (((size_t)(bb * NHc + h) * 64) + mtile) * 2;
        float inv = 1.f / (pL[t0 * 16 + mm] + pL[(t0 + 1) * 16 + mm]);
        int idx = mm * 32 + quad * 8;
        const unsigned short* p0 = pO + t0 * 512 + idx;
        const unsigned short* p1 = pO + (t0 + 1) * 512 + idx;
        ushort4 a0 = *(const ushort4*)p0;
        ushort4 a1 = *(const ushort4*)(p0 + 4);
        ushort4 b0 = *(const ushort4*)p1;
        ushort4 b1 = *(const ushort4*)(p1 + 4);
        bf16x8 af;
        unsigned short* afp = (unsigned short*)&af;
        afp[0] = f2bf((bf2f(a0.x) + bf2f(b0.x)) * inv);
        afp[1] = f2bf((bf2f(a0.y) + bf2f(b0.y)) * inv);
        afp[2] = f2bf((bf2f(a0.z) + bf2f(b0.z)) * inv);
        afp[3] = f2bf((bf2f(a0.w) + bf2f(b0.w)) * inv);
        afp[4] = f2bf((bf2f(a1.x) + bf2f(b1.x)) * inv);
        afp[5] = f2bf((bf2f(a1.y) + bf2f(b1.y)) * inv);
        afp[6] = f2bf((bf2f(a1.z) + bf2f(b1.z)) * inv);
        afp[7] = f2bf((bf2f(a1.w) + bf2f(b1.w)) * inv);
        bf16x8 w0 = *(const bf16x8*)(Wp0 + k0);
        bf16x8 w1 = *(const bf16x8*)(Wp1 + k0);
        acc[0] = __builtin_amdgcn_mfma_f32_16x16x32_bf16(af, w0, acc[0], 0, 0, 0);
        acc[1] = __builtin_amdgcn_mfma_f32_16x16x32_bf16(af, w1, acc[1], 0, 0, 0);
    }
    #pragma unroll
    for (int ch = 0; ch < 2; ch++) {
        int n = n0 + ch * 16 + col;
        float bv = bias[n];
        #pragma unroll
        for (int r = 0; r < 4; r++) {
            size_t mo = mb + quad * 4 + r;
            float v = acc[ch][r] + bv;
            out1[mo * N + n] = v + res[mo * N + n];
        }
    }
}

// ---------------- fused k+v projection (shared A fragments), 32n --------
__global__ __launch_bounds__(256) void mfma_kv(
    const unsigned short* __restrict__ A, const unsigned short* __restrict__ Wk,
    const unsigned short* __restrict__ Wv, const float* __restrict__ bk,
    const float* __restrict__ bv, unsigned short* __restrict__ kout,
    unsigned short* __restrict__ vout, int M, int K)
{
    int w = threadIdx.x >> 6, l = threadIdx.x & 63;
    int col = l & 15, quad = l >> 4;
    int mb = blockIdx.x * 64 + w * 16;
    int n0 = blockIdx.y * 32;
    const unsigned short* Ap = A + (size_t)(mb + col) * K + quad * 8;
    const unsigned short* Wk0 = Wk + (size_t)(n0 + col) * K + quad * 8;
    const unsigned short* Wk1 = Wk + (size_t)(n0 + 16 + col) * K + quad * 8;
    const unsigned short* Wv0 = Wv + (size_t)(n0 + col) * K + quad * 8;
    const unsigned short* Wv1 = Wv + (size_t)(n0 + 16 + col) * K + quad * 8;
    f32x4 ak[2] = {}, av[2] = {};
    #pragma unroll 4
    for (int k0 = 0; k0 < K; k0 += 32) {
        bf16x8 af = *(const bf16x8*)(Ap + k0);
        bf16x8 k0f = *(const bf16x8*)(Wk0 + k0);
        bf16x8 k1f = *(const bf16x8*)(Wk1 + k0);
        bf16x8 v0f = *(const bf16x8*)(Wv0 + k0);
        bf16x8 v1f = *(const bf16x8*)(Wv1 + k0);
        ak[0] = __builtin_amdgcn_mfma_f32_16x16x32_bf16(af, k0f, ak[0], 0, 0, 0);
        ak[1] = __builtin_amdgcn_mfma_f32_16x16x32_bf16(af, k1f, ak[1], 0, 0, 0);
        av[0] = __builtin_amdgcn_mfma_f32_16x16x32_bf16(af, v0f, av[0], 0, 0, 0);
        av[1] = __builtin_amdgcn_mfma_f32_16x16x32_bf16(af, v1f, av[1], 0, 0, 0);
    }
    int bb = mb >> 10, l0 = (mb & 1023) + quad * 4;
    #pragma unroll
    for (int ch = 0; ch < 2; ch++) {
        int n = n0 + ch * 16 + col;
        float bkv = bk[n], bvv = bv[n];
        #pragma unroll
        for (int r = 0; r < 4; r++)
            kout[(size_t)(mb + quad * 4 + r) * Cc + n] = f2bf(ak[ch][r] + bkv);
        ushort4 u;
        u.x = f2bf(av[ch][0] + bvv); u.y = f2bf(av[ch][1] + bvv);
        u.z = f2bf(av[ch][2] + bvv); u.w = f2bf(av[ch][3] + bvv);
        *(ushort4*)&vout[((size_t)(bb * Cc + n)) * NSc + l0] = u;
    }
}

// ---------------- Depthwise 7x7 conv (bf16 in, f32 out), LDS-staged ------
__global__ __launch_bounds__(256) void dwconv_kernel(
    const unsigned short* __restrict__ q, const float* __restrict__ wdw,
    const float* __restrict__ bdw, float* __restrict__ o_dw)
{
    int cg = blockIdx.x, bg = blockIdx.y;
    int b = bg / NGc, g = bg % NGc;
    __shared__ float wk_s[49];
    __shared__ float img[1024];
    const unsigned short* qp = q + (size_t)(b * Cc + g * CGc + cg) * Lc;
    if (threadIdx.x < 49) wk_s[threadIdx.x] = wdw[cg * 49 + threadIdx.x];
    #pragma unroll
    for (int i = 0; i < 4; i++)
        img[threadIdx.x + i * 256] = bf2f(qp[threadIdx.x + i * 256]);
    __syncthreads();
    float bias = bdw[cg];
    #pragma unroll
    for (int i = 0; i < 4; i++) {
        int hw = threadIdx.x + i * 256;
        int y = hw >> 5, xx = hw & 31;
        float acc = bias;
        #pragma unroll
        for (int ky = 0; ky < 7; ky++) {
            int yy = y + ky - 3;
            if (yy < 0 || yy > 31) continue;
            #pragma unroll
            for (int kx = 0; kx < 7; kx++) {
                int x2 = xx + kx - 3;
                if (x2 < 0 || x2 > 31) continue;
                acc += img[yy * 32 + x2] * wk_s[ky * 7 + kx];
            }
        }
        o_dw[(size_t)(bg * CGc + cg) * Lc + hw] = acc;
    }
}

// ---------------- fused offset head + grid-sample ------------------------
__global__ __launch_bounds__(256) void offsample_kernel(
    const float* __restrict__ o_dw, const float* __restrict__ lnw,
    const float* __restrict__ lnb, const float* __restrict__ pw,
    const unsigned short* __restrict__ xn, float* __restrict__ pos,
    unsigned short* __restrict__ xs)
{
    int hw = blockIdx.x * 4 + (threadIdx.x >> 6);
    int bg = blockIdx.y;
    int cg = threadIdx.x & 63;
    int b = bg / NGc, g = bg % NGc;
    float v = o_dw[(size_t)(bg * CGc + cg) * Lc + hw];
    float s = v;
    #pragma unroll
    for (int o = 32; o; o >>= 1) s += __shfl_down(s, o);
    s = __shfl(s, 0, 64);
    float mu = s * (1.f / CGc);
    float d = v - mu;
    float q2 = d * d;
    #pragma unroll
    for (int o = 32; o; o >>= 1) q2 += __shfl_down(q2, o);
    q2 = __shfl(q2, 0, 64);
    float rstd = rsqrtf(q2 * (1.f / CGc) + 1e-5f);
    float t = d * rstd * lnw[cg] + lnb[cg];
    float gl = gelu_f(t);
    float sy = gl * pw[cg];
    float sx = gl * pw[CGc + cg];
    #pragma unroll
    for (int o = 32; o; o >>= 1) {
        sy += __shfl_down(sy, o);
        sx += __shfl_down(sx, o);
    }
    sy = __shfl(sy, 0, 64);
    sx = __shfl(sx, 0, 64);
    int y = hw >> 5, xx = hw & 31;
    float py = tanhf(sy) * 0.0625f + ((y + 0.5f) * (2.f / Hh) - 1.f);
    float px = tanhf(sx) * 0.0625f + ((xx + 0.5f) * (2.f / Ww) - 1.f);
    if (cg == 0) {
        pos[((size_t)bg * Lc + hw) * 2 + 0] = py;
        pos[((size_t)bg * Lc + hw) * 2 + 1] = px;
    }
    float fx = (px + 1.f) * 0.5f * 31.f;
    float fy = (py + 1.f) * 0.5f * 31.f;
    float x0f = floorf(fx), y0f = floorf(fy);
    int x0 = (int)x0f, y0 = (int)y0f;
    float wx1 = fx - x0f, wy1 = fy - y0f;
    float wx0 = 1.f - wx1, wy0 = 1.f - wy1;
    const unsigned short* base = xn + (size_t)(b * Lc) * Cc + g * CGc + cg;
    float acc = 0.f;
    if (y0 >= 0 && y0 <= 31) {
        if (x0 >= 0 && x0 <= 31) acc += bf2f(base[(size_t)(y0 * 32 + x0) * Cc]) * wx0 * wy0;
        if (x0 + 1 >= 0 && x0 + 1 <= 31) acc += bf2f(base[(size_t)(y0 * 32 + x0 + 1) * Cc]) * wx1 * wy0;
    }
    if (y0 + 1 >= 0 && y0 + 1 <= 31) {
        if (x0 >= 0 && x0 <= 31) acc += bf2f(base[(size_t)((y0 + 1) * 32 + x0) * Cc]) * wx0 * wy1;
        if (x0 + 1 >= 0 && x0 + 1 <= 31) acc += bf2f(base[(size_t)((y0 + 1) * 32 + x0 + 1) * Cc]) * wx1 * wy1;
    }
    xs[((size_t)(b * NSc) + hw) * Cc + g * CGc + cg] = f2bf(acc);
}

// ---------------- MFMA flash attention v10: split-n x2, bf16 partials ----
// R16 structure (no fences, no atomics). Partials bf16 into dead xnbf/qb16
// region (no overlay race with qbf).
__global__ __launch_bounds__(256) void attn_kernel(
    const unsigned short* __restrict__ qbf, const unsigned short* __restrict__ kbf,
    const unsigned short* __restrict__ vtb, const float* __restrict__ pos,
    const unsigned short* __restrict__ rpet, unsigned short* __restrict__ pO,
    float* __restrict__ pL)
{
    __shared__ float o_smem[2112];               // o_s overlay [4][16][33]
    __shared__ unsigned short p_bf[4][16 * 72];  // per-wave P tile
    __shared__ float l_s[4][16];
    unsigned short* rpe_s = (unsigned short*)o_smem;  // [63][65] bf16*log2e

    int m0 = blockIdx.x * 16;
    int h = blockIdx.y >> 1, half = blockIdx.y & 1;
    int b = blockIdx.z;
    int tid = threadIdx.x;
    int w = tid >> 6, l = tid & 63;
    int col = l & 15, quad = l >> 4;

    {   // raw vector copy of the precomputed LDS image (4096 entries)
        const unsigned short* tbh = rpet + (size_t)h * 4096;
        #pragma unroll
        for (int i = 0; i < 4; i++) {
            int idx = (tid + i * 256) * 4;
            *(ushort4*)(rpe_s + idx) = *(const ushort4*)(tbh + idx);
        }
    }

    bf16x8 qfrag = *(const bf16x8*)(qbf +
        ((((size_t)(b * NHc + h)) * Lc + m0 + col) * 32 + quad * 8));

    float qgy = ((m0 >> 5) + 0.5f) * (2.f / 32.f) - 1.f;
    float qgx0 = (((m0 & 31) + quad * 4) + 0.5f) * (2.f / 32.f) - 1.f;

    const unsigned short* kb_ = kbf + (size_t)b * NSc * Cc + h * HCc;
    const unsigned short* vb_ = vtb + ((size_t)(b * Cc + h * HCc)) * NSc;
    const float2* pp = (const float2*)(pos + (size_t)(b * NGc + (h >> 1)) * NSc * 2);

    float run_l[4] = {0.f, 0.f, 0.f, 0.f};
    f32x4 O0 = {0.f, 0.f, 0.f, 0.f};
    f32x4 O1 = {0.f, 0.f, 0.f, 0.f};

    __syncthreads();   // rpe_s staged

    for (int it = 0; it < 2; it++) {
        int n0 = half * 512 + w * 128 + it * 64;
        // ---- QK^T ----
        f32x4 s[4];
        #pragma unroll
        for (int ch = 0; ch < 4; ch++) {
            bf16x8 kf = *(const bf16x8*)(kb_ +
                ((size_t)(n0 + ch * 16 + col) * Cc + quad * 8));
            f32x4 z = {0.f, 0.f, 0.f, 0.f};
            s[ch] = __builtin_amdgcn_mfma_f32_16x16x32_bf16(qfrag, kf, z, 0, 0, 0);
        }
        // ---- scale(log2e) + RPE bias from bf16 LDS table ----
        #pragma unroll
        for (int ch = 0; ch < 4; ch++) {
            int n = n0 + ch * 16 + col;
            float2 pyx = pp[n];
            float fy = ((qgy - pyx.x) * 0.5f + 1.f) * 31.f;
            float y0f = floorf(fy);
            int iy = (int)y0f;
            float wy1 = fy - y0f, wy0 = 1.f - wy1;
            bool y0ok = (unsigned)iy <= 62u;
            bool y1ok = (unsigned)(iy + 1) <= 62u;
            const unsigned short* r0 = rpe_s + iy * 65;
            float fx0 = ((qgx0 - pyx.y) * 0.5f + 1.f) * 31.f;
            #pragma unroll
            for (int r = 0; r < 4; r++) {
                float fx = fx0 + r * 0.96875f;
                float x0f = floorf(fx);
                int ix = (int)x0f;
                float wx1 = fx - x0f, wx0 = 1.f - wx1;
                bool x0ok = (unsigned)ix <= 62u;
                bool x1ok = (unsigned)(ix + 1) <= 62u;
                float bias = 0.f;
                if (y0ok) {
                    if (x0ok) bias += bf2f(r0[ix]) * wy0 * wx0;
                    if (x1ok) bias += bf2f(r0[ix + 1]) * wy0 * wx1;
                }
                if (y1ok) {
                    if (x0ok) bias += bf2f(r0[65 + ix]) * wy1 * wx0;
                    if (x1ok) bias += bf2f(r0[65 + ix + 1]) * wy1 * wx1;
                }
                // 0.17677669529663688 * log2(e)
                s[ch][r] = s[ch][r] * 0.25506974f + bias;
            }
        }
        // ---- max-free softmax accumulation (exp2 domain) ----
        float rowsum[4] = {0.f, 0.f, 0.f, 0.f};
        #pragma unroll
        for (int ch = 0; ch < 4; ch++)
            #pragma unroll
            for (int r = 0; r < 4; r++) {
                float e = exp2f(s[ch][r]);
                s[ch][r] = e;
                rowsum[r] += e;
            }
        #pragma unroll
        for (int r = 0; r < 4; r++) run_l[r] += rowsum[r];
        // ---- P -> wave-private LDS (C-layout -> A-layout) ----
        #pragma unroll
        for (int ch = 0; ch < 4; ch++)
            #pragma unroll
            for (int r = 0; r < 4; r++)
                p_bf[w][(quad * 4 + r) * 72 + ch * 16 + col] = f2bf(s[ch][r]);
        // ---- PV ----
        #pragma unroll
        for (int hn = 0; hn < 2; hn++) {
            bf16x8 pf = *(const bf16x8*)&p_bf[w][col * 72 + hn * 32 + quad * 8];
            bf16x8 v0 = *(const bf16x8*)(vb_ +
                ((size_t)col * NSc + n0 + hn * 32 + quad * 8));
            O0 = __builtin_amdgcn_mfma_f32_16x16x32_bf16(pf, v0, O0, 0, 0, 0);
            bf16x8 v1 = *(const bf16x8*)(vb_ +
                ((size_t)(col + 16) * NSc + n0 + hn * 32 + quad * 8));
            O1 = __builtin_amdgcn_mfma_f32_16x16x32_bf16(pf, v1, O1, 0, 0, 0);
        }
    }
    // ---- reduce row-sums across the quad's 16 lanes ----
    #pragma unroll
    for (int r = 0; r < 4; r++) {
        float sm = run_l[r];
        #pragma unroll
        for (int msk = 1; msk < 16; msk <<= 1)
            sm += __shfl_xor(sm, msk);
        run_l[r] = sm;
    }
    __syncthreads();   // all rpe_s reads done before o_s overlay
    float* o_s = o_smem;
    #pragma unroll
    for (int r = 0; r < 4; r++) {
        int m = quad * 4 + r;
        o_s[w * 528 + m * 33 + col] = O0[r];
        o_s[w * 528 + m * 33 + col + 16] = O1[r];
    }
    if (col == 0) {
        #pragma unroll
        for (int r = 0; r < 4; r++)
            l_s[w][quad * 4 + r] = run_l[r];
    }
    __syncthreads();
    // ---- cross-wave sums -> bf16 partials (plain sums, max-free) ----
    size_t tile = (((size_t)(b * NHc + h) * 64) + blockIdx.x) * 2 + half;
    for (int i = tid; i < 512; i += 256) {
        int m = i >> 5, c = i & 31;
        float osum = o_s[0 * 528 + m * 33 + c] + o_s[1 * 528 + m * 33 + c]
                   + o_s[2 * 528 + m * 33 + c] + o_s[3 * 528 + m * 33 + c];
        pO[tile * 512 + i] = f2bf(osum);
        if (c == 0)
            pL[tile * 16 + m] = l_s[0][m] + l_s[1][m] + l_s[2][m] + l_s[3][m];
    }
}

extern "C" void kernel_launch(void* const* d_in, const int* in_sizes, int n_in,
                              void* d_out, int out_size, void* d_ws, size_t ws_size,
                              hipStream_t stream)
{
    const float* x    = (const float*)d_in[0];
    const float* n1w  = (const float*)d_in[1];
    const float* n1b  = (const float*)d_in[2];
    const float* wq   = (const float*)d_in[3];
    const float* bq   = (const float*)d_in[4];
    const float* wk   = (const float*)d_in[5];
    const float* bk   = (const float*)d_in[6];
    const float* wv   = (const float*)d_in[7];
    const float* bv   = (const float*)d_in[8];
    const float* wo   = (const float*)d_in[9];
    const float* bo   = (const float*)d_in[10];
    const float* dw_w = (const float*)d_in[11];
    const float* dw_b = (const float*)d_in[12];
    const float* lnw  = (const float*)d_in[13];
    const float* lnb  = (const float*)d_in[14];
    const float* pw_w = (const float*)d_in[15];
    const float* rpe  = (const float*)d_in[16];
    const float* n2w  = (const float*)d_in[17];
    const float* n2b  = (const float*)d_in[18];
    const float* fc1w = (const float*)d_in[19];
    const float* fc1b = (const float*)d_in[20];
    const float* fc2w = (const float*)d_in[21];
    const float* fc2b = (const float*)d_in[22];
    float* out = (float*)d_out;

    float* ws = (float*)d_ws;
    unsigned short* xnbf = (unsigned short*)ws;                  // (B,L,C) bf16
    unsigned short* qb16 = (unsigned short*)(ws + 393216);       // (B,C,L) bf16
    unsigned short* qbf  = (unsigned short*)(ws + 1179648);      // (B,NH,L,32) bf16
    unsigned short* h1bf = (unsigned short*)ws;                  // (B*L,HID) bf16 (overlay)
    // attn partials: bf16 pO + f32 pL entirely inside dead xnbf/qb16 region
    unsigned short* pO = (unsigned short*)ws;                    // 3072*512 us = [0,786432) f
    float* pL          = ws + 786432;                            // 3072*16 f32
    float* odw   = ws + 1671168;                                 // (BG,CG,L) f32
    unsigned short* xln2bf = (unsigned short*)(ws + 1671168);    // overlay odw
    float* posb  = ws + 2457600;                                 // (BG,NS,2) f32
    unsigned short* xsbf = (unsigned short*)(ws + 2482176);      // (B,NS,C) bf16
    unsigned short* kbf  = (unsigned short*)(ws + 2875392);      // (B,NS,C) bf16
    unsigned short* vtb  = (unsigned short*)(ws + 3268608);      // (B,C,NS) bf16
    float* x2    = ws + 4055040;                                 // (B,L,C) f32
    unsigned short* wqbf   = (unsigned short*)(ws + 4841472);
    unsigned short* wkbf   = (unsigned short*)(ws + 4915200);
    unsigned short* wvbf   = (unsigned short*)(ws + 4988928);
    unsigned short* wobf   = (unsigned short*)(ws + 5062656);
    unsigned short* fc1wbf = (unsigned short*)(ws + 5136384);
    unsigned short* fc2wbf = (unsigned short*)(ws + 5431296);
    unsigned short* rpet   = (unsigned short*)(ws + 5726208);    // 12*4096 us

    // 0. fused prep: weight casts + rpe table + LN1 (one launch)
    prep_kernel<<<2944, 256, 0, stream>>>(
        wq, wk, wv, wo, fc1w, fc2w, wqbf, wkbf, wvbf, wobf, fc1wbf, fc2wbf,
        rpe, rpet, x, n1w, n1b, xnbf);
    // 1. q projection (MFMA): dual-store bf16 (B,C,L) + bf16 (B,NH,L,32)
    mfma_gemm<3><<<dim3(Bc * Lc / 64, Cc / 32), 256, 0, stream>>>(
        xnbf, wqbf, bq, x, qb16, qbf, Bc * Lc, Cc, Cc);
    // 2. depthwise 7x7 (bf16 in)
    dwconv_kernel<<<dim3(CGc, BGc), 256, 0, stream>>>(qb16, dw_w, dw_b, odw);
    // 3. fused offset head + grid-sample -> pos + xsbf
    offsample_kernel<<<dim3(Lc / 4, BGc), 256, 0, stream>>>(
        odw, lnw, lnb, pw_w, xnbf, posb, xsbf);
    // 4. fused k+v projection
    mfma_kv<<<dim3(Bc * NSc / 64, Cc / 32), 256, 0, stream>>>(
        xsbf, wkbf, wvbf, bk, bv, kbf, vtb, Bc * NSc, Cc);
    // 5. MFMA flash attention, n-split x2 -> bf16 partials
    attn_kernel<<<dim3(Lc / 16, NHc * 2, Bc), 256, 0, stream>>>(
        qbf, kbf, vtb, posb, rpet, pO, pL);
    // 6. out projection with fused merge + residual -> x2 f32 (B,L,C)
    mfma_oproj<<<dim3(Bc * Lc / 64, Cc / 32), 256, 0, stream>>>(
        pO, pL, wobf, bo, x, x2, Bc * Lc, Cc, Cc);
    // 7. LN2 -> bf16
    ln_kernel<<<Bc * Lc, 128, 0, stream>>>(x2, n2w, n2b, xln2bf);
    // 8. fc1 + GELU (MFMA) -> h1 bf16
    mfma_gemm<1><<<dim3(Bc * Lc / 64, HIDc / 32), 256, 0, stream>>>(
        xln2bf, fc1wbf, fc1b, x2, h1bf, h1bf, Bc * Lc, HIDc, Cc);
    // 9. fc2 + residual (MFMA) -> out f32
    mfma_gemm<2><<<dim3(Bc * Lc / 64, Cc / 32), 256, 0, stream>>>(
        h1bf, fc2wbf, fc2b, x2, out, out, Bc * Lc, Cc, HIDc);
}